// Round 6
// baseline (7179.766 us; speedup 1.0000x reference)
//
#include <hip/hip_runtime.h>
#include <hip/hip_bf16.h>

#define N_NODES 100000
#define N_EDGES 1000000
#define NLAYERS 10

typedef __hip_bfloat16 bf16;

// flag-aware float load: isbf=1 -> treat p as bf16 array, else fp32
__device__ __forceinline__ float ldf(const void* p, long i, int isbf){
  if (isbf){
    unsigned short u = ((const unsigned short*)p)[i];
    union{unsigned u; float f;} c; c.u = ((unsigned)u) << 16; return c.f;
  }
  return ((const float*)p)[i];
}

// edge accessors: i64=1 -> ei is int64 words (low word at 2*idx), else int32
__device__ __forceinline__ int esrc(const int* ei, int e, int i64){
  return i64 ? ei[2*e] : ei[e];
}
__device__ __forceinline__ int edst(const int* ei, int e, int i64){
  return i64 ? ei[2*N_EDGES + 2*e] : ei[N_EDGES + e];
}

// ---------------- dtype detection: x bf16-vs-f32, edge int64-vs-int32 ----------------
__global__ __launch_bounds__(256) void k_detect(const unsigned* __restrict__ xw,
                                                const int* __restrict__ ei,
                                                int* __restrict__ flag,
                                                int* __restrict__ eflag){
  __shared__ int s[256];
  int tid = threadIdx.x;
  int cnt = 0;
  for (int i = 0; i < 16; i++){
    unsigned u = xw[tid*16 + i];
    unsigned lo = u & 0xffffu;
    unsigned e = (lo >> 7) & 0xff;
    if ((e >= 96 && e <= 150) || lo == 0) cnt++;
  }
  s[tid] = cnt; __syncthreads();
  for (int o = 128; o > 0; o >>= 1){ if (tid < o) s[tid] += s[tid+o]; __syncthreads(); }
  if (tid == 0){
    *flag = (s[0] >= 3000) ? 1 : 0;   // bf16 ~4096 hits, f32 ~880
    int nz = 0;                        // int64 => all high words zero
    for (int j = 1; j < 4096; j += 2) nz |= ei[j];
    *eflag = (nz == 0) ? 1 : 0;
  }
}

// ---------------- CSR build ----------------
__global__ __launch_bounds__(256) void k_count(const int* __restrict__ ei,
    int* __restrict__ cnt, const int* __restrict__ eflag){
  int i64 = *eflag;
  int e = blockIdx.x*256 + threadIdx.x;
  if (e < N_EDGES) atomicAdd(&cnt[edst(ei, e, i64)], 1);
}

__global__ __launch_bounds__(1024) void k_scan(int* __restrict__ cur, int* __restrict__ rowptr){
  __shared__ int lds[1024];
  __shared__ int carry_s;
  int tid = threadIdx.x;
  if (tid == 0) carry_s = 0;
  __syncthreads();
  for (int base = 0; base < N_NODES; base += 1024){
    int i = base + tid;
    int v = (i < N_NODES) ? cur[i] : 0;
    lds[tid] = v;
    __syncthreads();
    for (int off = 1; off < 1024; off <<= 1){
      int t = (tid >= off) ? lds[tid - off] : 0;
      __syncthreads();
      lds[tid] += t;
      __syncthreads();
    }
    int incl = lds[tid];
    int c = carry_s;
    __syncthreads();
    if (tid == 1023) carry_s = c + incl;
    if (i < N_NODES){ int ex = c + incl - v; rowptr[i] = ex; cur[i] = ex; }
    __syncthreads();
  }
  if (tid == 0) rowptr[N_NODES] = carry_s;
}

__global__ __launch_bounds__(256) void k_fill(const int* __restrict__ ei,
    int* __restrict__ cursor, int* __restrict__ colsrc, const int* __restrict__ eflag){
  int i64 = *eflag;
  int e = blockIdx.x*256 + threadIdx.x;
  if (e < N_EDGES){
    int d = edst(ei, e, i64);
    int p = atomicAdd(&cursor[d], 1);
    colsrc[p] = esrc(ei, e, i64);
  }
}

// ---------------- convert ALL params to planar fp32 ----------------
// pf (floats): Wq@0(64000) Wk@64000 Wv@128000 Wo@192000 W1@256000(128000)
// W2@384000(128000) bo@512000(800) b1@512800(1600) b2@514400(800)
// We@515200(720) be@515920(80) Wr0@516000(3200) br0@519200(40)
// Wr1@519240(800) br1@520040(20) Wr2@520060(80) br2@520140(4) -> 520144 total
__global__ __launch_bounds__(256) void k_cvt(
    const void* Wq, const void* Wk, const void* Wv, const void* Wo,
    const void* W1, const void* W2, const void* bo, const void* b1,
    const void* b2, const void* We, const void* be,
    const void* Wr0, const void* br0, const void* Wr1, const void* br1,
    const void* Wr2, const void* br2,
    float* __restrict__ pf, const int* __restrict__ flagp){
  const int isbf = *flagp;
  int idx = blockIdx.x*256 + threadIdx.x;
  if (idx >= 520144) return;
  const void* src; long off;
  if      (idx < 64000)  { src=Wq;  off=idx; }
  else if (idx < 128000) { src=Wk;  off=idx-64000; }
  else if (idx < 192000) { src=Wv;  off=idx-128000; }
  else if (idx < 256000) { src=Wo;  off=idx-192000; }
  else if (idx < 384000) { src=W1;  off=idx-256000; }
  else if (idx < 512000) { src=W2;  off=idx-384000; }
  else if (idx < 512800) { src=bo;  off=idx-512000; }
  else if (idx < 514400) { src=b1;  off=idx-512800; }
  else if (idx < 515200) { src=b2;  off=idx-514400; }
  else if (idx < 515920) { src=We;  off=idx-515200; }
  else if (idx < 516000) { src=be;  off=idx-515920; }
  else if (idx < 519200) { src=Wr0; off=idx-516000; }
  else if (idx < 519240) { src=br0; off=idx-519200; }
  else if (idx < 520040) { src=Wr1; off=idx-519240; }
  else if (idx < 520060) { src=br1; off=idx-520040; }
  else if (idx < 520140) { src=Wr2; off=idx-520060; }
  else                   { src=br2; off=idx-520140; }
  pf[idx] = ldf(src, off, isbf);
}

// ---------------- embedding: h = x @ We + be (fp32) ----------------
__global__ __launch_bounds__(256) void k_embed(const void* __restrict__ x,
    const float* __restrict__ WeF, const float* __restrict__ beF,
    float* __restrict__ h, const int* __restrict__ flagp){
  __shared__ float Wl[720];
  __shared__ float bl[80];
  const int isbf = *flagp;
  int tid = threadIdx.x;
  for (int i = tid; i < 720; i += 256) Wl[i] = WeF[i];
  if (tid < 80) bl[tid] = beF[tid];
  __syncthreads();
  long idx = (long)blockIdx.x*256 + tid;   // exactly N_NODES*80
  int n = (int)(idx / 80); int c = (int)(idx - (long)n*80);
  float s = bl[c];
  #pragma unroll
  for (int k = 0; k < 9; k++) s = fmaf(ldf(x, (long)n*9 + k, isbf), Wl[k*80 + c], s);
  h[idx] = s;
}

// ---------------- fp32 GEMM, sections of 40 output cols ----------------
// A rows: k<ksplit from A[row*lda+k], else A2[row*lda+(k-ksplit)].
// W[(kc*80+kk)*ldw + sec*wsec + nn]; out[row*ldc + sec*osec + c] (+bias/relu/resid).
template<int NSEC, int NKC>
__global__ __launch_bounds__(256) void k_gemm(
    const float* __restrict__ A, const float* __restrict__ A2, int ksplit, int lda,
    const float* __restrict__ W, int ldw, int wsec,
    const float* __restrict__ bias,
    const float* __restrict__ resid, int relu,
    float* __restrict__ out, int ldc, long osec){
  constexpr int ASR = 84;                 // pad: conflict-free broadcast reads
  __shared__ float As[64*ASR];
  __shared__ float Ws[80*40];
  const int tid  = threadIdx.x;
  const int row0 = blockIdx.x*64;
  const int r    = tid >> 2;              // 0..63 (row)
  const int cg   = tid & 3;               // col group: cols cg*10..cg*10+9
  float2 acc[NSEC][5];
  #pragma unroll
  for (int s = 0; s < NSEC; s++)
    #pragma unroll
    for (int i = 0; i < 5; i++) acc[s][i] = make_float2(0.f, 0.f);

  for (int kc = 0; kc < NKC; kc++){
    __syncthreads();
    { // stage A chunk [64 x 80] as float4 (no chunk straddles ksplit: 40|80 are x4)
      const int K0 = kc*80;
      #pragma unroll
      for (int j = 0; j < 5; j++){
        int i4 = tid + 256*j;                       // 0..1279
        int rr = i4/20; int k4 = (i4 - rr*20)*4;    // k4 in {0,4,...,76}
        int row = row0 + rr;
        float4 v = make_float4(0.f,0.f,0.f,0.f);
        if (row < N_NODES){
          int k = K0 + k4;
          const float* p = (k < ksplit) ? (A  + (long)row*lda + k)
                                        : (A2 + (long)row*lda + (k - ksplit));
          v = *(const float4*)p;
        }
        *(float4*)(&As[rr*ASR + k4]) = v;
      }
    }
    #pragma unroll
    for (int sec = 0; sec < NSEC; sec++){
      __syncthreads();
      for (int i = tid; i < 3200; i += 256){   // stage W chunk [80 x 40]
        int kk = i/40; int nn = i - kk*40;
        Ws[i] = W[(long)(kc*80 + kk)*ldw + sec*wsec + nn];
      }
      __syncthreads();
      const float* ar = &As[r*ASR];
      #pragma unroll 8
      for (int k = 0; k < 80; k++){
        float a = ar[k];
        const float2* wr = (const float2*)&Ws[k*40 + cg*10];
        #pragma unroll
        for (int i = 0; i < 5; i++){
          float2 w = wr[i];
          acc[sec][i].x = fmaf(a, w.x, acc[sec][i].x);
          acc[sec][i].y = fmaf(a, w.y, acc[sec][i].y);
        }
      }
    }
  }
  int row = row0 + r;
  if (row < N_NODES){
    #pragma unroll
    for (int sec = 0; sec < NSEC; sec++){
      #pragma unroll
      for (int i = 0; i < 5; i++){
        #pragma unroll
        for (int t = 0; t < 2; t++){
          int c = cg*10 + 2*i + t;
          float val = t ? acc[sec][i].y : acc[sec][i].x;
          if (bias) val += bias[sec*40 + c];
          if (relu) val = fmaxf(val, 0.f);
          long o = (long)row*ldc + sec*osec + c;
          if (resid) val += resid[o];
          out[o] = val;
        }
      }
    }
  }
}

// ---------------- edge-softmax attention, fp32, half-head pass (4 heads) -----------
// Qg/Kg/Vg: [N,40] fp32. Output overwrites Qg row n (only node n reads Q[n]).
__global__ __launch_bounds__(256) void k_attn(
    float* __restrict__ Qg, const float* __restrict__ Kg, const float* __restrict__ Vg,
    const int* __restrict__ rowptr, const int* __restrict__ colsrc){
  int id = blockIdx.x*256 + threadIdx.x;
  int n = id >> 2; int hh = id & 3;
  if (n >= N_NODES) return;
  float* qp = Qg + (long)n*40 + hh*10;
  float qv[10];
  #pragma unroll
  for (int i = 0; i < 5; i++){ float2 t = *(const float2*)(qp + 2*i); qv[2*i]=t.x; qv[2*i+1]=t.y; }
  float acc[10];
  #pragma unroll
  for (int i = 0; i < 10; i++) acc[i] = 0.f;
  float z = 0.f;
  int e0 = rowptr[n], e1 = rowptr[n+1];
  for (int j = e0; j < e1; j++){
    int src = colsrc[j];
    const float* kp = Kg + (long)src*40 + hh*10;
    const float* vp = Vg + (long)src*40 + hh*10;
    float dot = 0.f;
    #pragma unroll
    for (int i = 0; i < 5; i++){
      float2 kv = *(const float2*)(kp + 2*i);
      dot = fmaf(kv.x, qv[2*i], dot);
      dot = fmaf(kv.y, qv[2*i+1], dot);
    }
    float sc = fminf(fmaxf(dot * 0.31622776601683794f, -5.f), 5.f);  // /sqrt(10), clamp
    float s = __expf(sc);
    z += s;
    #pragma unroll
    for (int i = 0; i < 5; i++){
      float2 vv = *(const float2*)(vp + 2*i);
      acc[2*i]   = fmaf(s, vv.x, acc[2*i]);
      acc[2*i+1] = fmaf(s, vv.y, acc[2*i+1]);
    }
  }
  float inv = 1.f / (z + 1e-6f);
  #pragma unroll
  for (int i = 0; i < 5; i++){
    float2 o; o.x = acc[2*i]*inv; o.y = acc[2*i+1]*inv;
    *(float2*)(qp + 2*i) = o;
  }
}

// ---------------- MLP readout 80->40->20->4, fp32 output ----------------
__global__ __launch_bounds__(256) void k_readout(const float* __restrict__ h,
    const float* __restrict__ roF,  // Wr0@0 br0@3200 Wr1@3240 br1@4040 Wr2@4060 br2@4140
    float* __restrict__ out){
  __shared__ float w0[3200], w1[800], w2[80], bb0[40], bb1[20], bb2[4];
  int tid = threadIdx.x;
  for (int i = tid; i < 3200; i += 256) w0[i] = roF[i];
  for (int i = tid; i < 800;  i += 256) w1[i] = roF[3240 + i];
  if (tid < 80) w2[tid]  = roF[4060 + tid];
  if (tid < 40) bb0[tid] = roF[3200 + tid];
  if (tid < 20) bb1[tid] = roF[4040 + tid];
  if (tid < 4)  bb2[tid] = roF[4140 + tid];
  __syncthreads();
  int n = blockIdx.x*256 + tid;
  if (n >= N_NODES) return;
  float t0[40];
  #pragma unroll
  for (int c = 0; c < 40; c++) t0[c] = bb0[c];
  for (int k4 = 0; k4 < 20; k4++){
    float4 hv = *(const float4*)(h + (size_t)n*80 + k4*4);
    float hx[4] = {hv.x, hv.y, hv.z, hv.w};
    #pragma unroll
    for (int j = 0; j < 4; j++){
      int k = k4*4 + j;
      #pragma unroll
      for (int c = 0; c < 40; c++) t0[c] = fmaf(hx[j], w0[k*40 + c], t0[c]);
    }
  }
  float t1[20];
  #pragma unroll
  for (int c = 0; c < 20; c++) t1[c] = bb1[c];
  for (int k = 0; k < 40; k++){
    float a = fmaxf(t0[k], 0.f);
    #pragma unroll
    for (int c = 0; c < 20; c++) t1[c] = fmaf(a, w1[k*20 + c], t1[c]);
  }
  float o[4];
  #pragma unroll
  for (int c = 0; c < 4; c++) o[c] = bb2[c];
  for (int k = 0; k < 20; k++){
    float a = fmaxf(t1[k], 0.f);
    #pragma unroll
    for (int c = 0; c < 4; c++) o[c] = fmaf(a, w2[k*4 + c], o[c]);
  }
  #pragma unroll
  for (int c = 0; c < 4; c++) out[n*4 + c] = o[c];
}

// ---------------- launch ----------------
extern "C" void kernel_launch(void* const* d_in, const int* in_sizes, int n_in,
                              void* d_out, int out_size, void* d_ws, size_t ws_size,
                              hipStream_t stream){
  const void* x   = d_in[0];
  const int*  ei  = (const int*)d_in[1];
  const void* We  = d_in[2];
  const void* be  = d_in[3];
  const void* Wq  = d_in[4];
  const void* Wk  = d_in[5];
  const void* Wv  = d_in[6];
  const void* Wo  = d_in[7];
  const void* bo  = d_in[8];
  const void* W1  = d_in[9];
  const void* b1  = d_in[10];
  const void* W2  = d_in[11];
  const void* b2  = d_in[12];
  const void* Wr0 = d_in[13];
  const void* br0 = d_in[14];
  const void* Wr1 = d_in[15];
  const void* br1 = d_in[16];
  const void* Wr2 = d_in[17];
  const void* br2 = d_in[18];

  char* ws = (char*)d_ws;
  int*   flag   = (int*)(ws + 0);
  int*   eflag  = (int*)(ws + 4);
  float* h      = (float*)(ws + 64);            // N*80 fp32 = 32,000,000 B
  float* B      = (float*)(ws + 32000064);      // 64 MB region: 4 slots of 4e6 floats
  float* pf     = (float*)(ws + 96000064);      // 520144*4 = 2,080,576 B
  int*   rowptr = (int*)(ws + 98080640);        // 400,004 B
  int*   colsrc = (int*)(ws + 98480704);        // 4,000,000 B -> ends 102,480,704
  int*   cursor = (int*)B;                      // aliases B (dead before layer loop)
  float* out    = (float*)d_out;                // fp32 output

  const long SLOT = 4000000;                    // floats per 16MB slot
  const float* WoF = pf + 192000;
  const float* W1F = pf + 256000;
  const float* W2F = pf + 384000;
  const float* boF = pf + 512000;
  const float* b1F = pf + 512800;
  const float* b2F = pf + 514400;
  const float* WeF = pf + 515200;
  const float* beF = pf + 515920;
  const float* roF = pf + 516000;

  k_detect<<<1, 256, 0, stream>>>((const unsigned*)x, ei, flag, eflag);
  hipMemsetAsync(cursor, 0, N_NODES*sizeof(int), stream);
  k_count<<<(N_EDGES+255)/256, 256, 0, stream>>>(ei, cursor, eflag);
  k_scan<<<1, 1024, 0, stream>>>(cursor, rowptr);
  k_fill<<<(N_EDGES+255)/256, 256, 0, stream>>>(ei, cursor, colsrc, eflag);
  k_cvt<<<2032, 256, 0, stream>>>(Wq, Wk, Wv, Wo, W1, W2, bo, b1, b2, We, be,
                                  Wr0, br0, Wr1, br1, Wr2, br2, pf, flag);
  k_embed<<<(N_NODES*80)/256, 256, 0, stream>>>(x, WeF, beF, h, flag);

  const int gblk = (N_NODES + 63) / 64;     // 1563
  const int ablk = (N_NODES*4 + 255) / 256; // 1563
  for (int l = 0; l < NLAYERS; l++){
    for (int g = 0; g < 2; g++){
      // QKV for heads g*4..g*4+3: sections (Wq|Wk|Wv) cols g*40..+40
      // out slots S_g, S_{g+1}, S_{g+2}
      k_gemm<3,1><<<gblk, 256, 0, stream>>>(
          h, h, 80, 80,
          pf + l*6400 + g*40, 80, 64000,
          nullptr, nullptr, 0,
          B + g*SLOT, 40, SLOT);
      // attention pass g: Q=S_g (overwritten with attn), K=S_{g+1}, V=S_{g+2}
      k_attn<<<ablk, 256, 0, stream>>>(
          B + g*SLOT, B + (g+1)*SLOT, B + (g+2)*SLOT, rowptr, colsrc);
    }
    // O-proj + residual: h += [attn0|attn1] @ Wo + bo   (attn0@S0, attn1@S1, lda=40)
    k_gemm<2,1><<<gblk, 256, 0, stream>>>(
        B, B + SLOT, 40, 40,
        WoF + l*6400, 80, 40,
        boF + l*80, h, 0,
        h, 80, 40);
    // FFN1: T = relu(h @ W1 + b1), T = B[N,160]
    k_gemm<4,1><<<gblk, 256, 0, stream>>>(
        h, h, 80, 80,
        W1F + l*12800, 160, 40,
        b1F + l*160, nullptr, 1,
        B, 160, 40);
    // FFN2 + residual: h += T @ W2 + b2
    k_gemm<2,2><<<gblk, 256, 0, stream>>>(
        B, B, 160, 160,
        W2F + l*12800, 80, 40,
        b2F + l*80, h, 0,
        h, 80, 40);
  }
  k_readout<<<(N_NODES+255)/256, 256, 0, stream>>>(h, roF, out);
}

// Round 7
// 3889.046 us; speedup vs baseline: 1.8462x; 1.8462x over previous
//
#include <hip/hip_runtime.h>
#include <hip/hip_bf16.h>

#define N_NODES 100000
#define N_EDGES 1000000
#define NLAYERS 10

typedef __hip_bfloat16 bf16;
typedef __attribute__((ext_vector_type(8))) short short8;
typedef __attribute__((ext_vector_type(4))) float f32x4;

// flag-aware float load: isbf=1 -> treat p as bf16 array, else fp32
__device__ __forceinline__ float ldf(const void* p, long i, int isbf){
  if (isbf){
    unsigned short u = ((const unsigned short*)p)[i];
    union{unsigned u; float f;} c; c.u = ((unsigned)u) << 16; return c.f;
  }
  return ((const float*)p)[i];
}

__device__ __forceinline__ int esrc(const int* ei, int e, int i64){
  return i64 ? ei[2*e] : ei[e];
}
__device__ __forceinline__ int edst(const int* ei, int e, int i64){
  return i64 ? ei[2*N_EDGES + 2*e] : ei[N_EDGES + e];
}

// split fp32 -> bf16 hi (truncate) + bf16 lo (residual)
__device__ __forceinline__ void split8(const float* p, short8& hi, short8& lo){
  float4 a = *(const float4*)p; float4 b = *(const float4*)(p+4);
  float v[8] = {a.x,a.y,a.z,a.w,b.x,b.y,b.z,b.w};
  #pragma unroll
  for (int i = 0; i < 8; i++){
    union{float f; unsigned u;} t; t.f = v[i];
    unsigned hu = t.u & 0xffff0000u;
    hi[i] = (short)(hu >> 16);
    union{unsigned u; float f;} hf; hf.u = hu;
    union{float f; unsigned u;} t2; t2.f = v[i] - hf.f;
    lo[i] = (short)(t2.u >> 16);
  }
}

// ---------------- dtype detection ----------------
__global__ __launch_bounds__(256) void k_detect(const unsigned* __restrict__ xw,
                                                const int* __restrict__ ei,
                                                int* __restrict__ flag,
                                                int* __restrict__ eflag){
  __shared__ int s[256];
  int tid = threadIdx.x;
  int cnt = 0;
  for (int i = 0; i < 16; i++){
    unsigned u = xw[tid*16 + i];
    unsigned lo = u & 0xffffu;
    unsigned e = (lo >> 7) & 0xff;
    if ((e >= 96 && e <= 150) || lo == 0) cnt++;
  }
  s[tid] = cnt; __syncthreads();
  for (int o = 128; o > 0; o >>= 1){ if (tid < o) s[tid] += s[tid+o]; __syncthreads(); }
  if (tid == 0){
    *flag = (s[0] >= 3000) ? 1 : 0;
    int nz = 0;
    for (int j = 1; j < 4096; j += 2) nz |= ei[j];
    *eflag = (nz == 0) ? 1 : 0;
  }
}

// ---------------- CSR build ----------------
__global__ __launch_bounds__(256) void k_count(const int* __restrict__ ei,
    int* __restrict__ cnt, const int* __restrict__ eflag){
  int i64 = *eflag;
  int e = blockIdx.x*256 + threadIdx.x;
  if (e < N_EDGES) atomicAdd(&cnt[edst(ei, e, i64)], 1);
}

// multi-block scan: 98 blocks x 1024
__global__ __launch_bounds__(1024) void k_scan1(const int* __restrict__ cnt,
    int* __restrict__ rowptr, int* __restrict__ bsum){
  __shared__ int lds[1024];
  int tid = threadIdx.x;
  int i = blockIdx.x*1024 + tid;
  int v = (i < N_NODES) ? cnt[i] : 0;
  lds[tid] = v; __syncthreads();
  for (int off = 1; off < 1024; off <<= 1){
    int t = (tid >= off) ? lds[tid - off] : 0;
    __syncthreads();
    lds[tid] += t;
    __syncthreads();
  }
  if (i < N_NODES) rowptr[i] = lds[tid] - v;     // local exclusive
  if (tid == 1023) bsum[blockIdx.x] = lds[1023];
}

__global__ __launch_bounds__(128) void k_scan2(int* __restrict__ bsum, int* __restrict__ rowptr){
  __shared__ int lds[128];
  int tid = threadIdx.x;
  int v = (tid < 98) ? bsum[tid] : 0;
  lds[tid] = v; __syncthreads();
  for (int off = 1; off < 128; off <<= 1){
    int t = (tid >= off) ? lds[tid - off] : 0;
    __syncthreads();
    lds[tid] += t;
    __syncthreads();
  }
  if (tid < 98) bsum[tid] = lds[tid] - v;        // exclusive block offsets
  if (tid == 127) rowptr[N_NODES] = lds[127];
}

__global__ __launch_bounds__(1024) void k_scan3(int* __restrict__ rowptr,
    int* __restrict__ cursor, const int* __restrict__ bsum){
  int i = blockIdx.x*1024 + threadIdx.x;
  if (i < N_NODES){
    int r = rowptr[i] + bsum[blockIdx.x];
    rowptr[i] = r;
    cursor[i] = r;
  }
}

__global__ __launch_bounds__(256) void k_fill(const int* __restrict__ ei,
    int* __restrict__ cursor, unsigned short* __restrict__ c16,
    unsigned char* __restrict__ c8, const int* __restrict__ eflag){
  int i64 = *eflag;
  int e = blockIdx.x*256 + threadIdx.x;
  if (e < N_EDGES){
    int d = edst(ei, e, i64);
    int p = atomicAdd(&cursor[d], 1);
    int s = esrc(ei, e, i64);
    c16[p] = (unsigned short)(s & 0xffff);
    c8[p]  = (unsigned char)(s >> 16);
  }
}

// ---------------- param prep: split+swizzle weights, small params fp32 ----------------
// Wswz entry layout per GEMM: [(kb*NTcols + n)*32 + kk], NTcols = NT*16.
// bases (elements): qkv (l,g): (l*2+g)*13824   total 276480
//                   oproj:     276480 + l*7680   total 76800
//                   ffn1:      353280 + l*15360  total 153600
//                   ffn2:      506880 + l*12800  total 128000  -> 634880
// pfS floats: bo@0(800) b1@800(1600) b2@2400(800) We@3200(720) be@3920(80)
//             Wr0@4000 br0@7200 Wr1@7240 br1@8040 Wr2@8060 br2@8140 -> 8144
__global__ __launch_bounds__(256) void k_prep(
    const void* Wq, const void* Wk, const void* Wv, const void* Wo,
    const void* W1, const void* W2, const void* bo, const void* b1,
    const void* b2, const void* We, const void* be,
    const void* Wr0, const void* br0, const void* Wr1, const void* br1,
    const void* Wr2, const void* br2,
    short* __restrict__ whi, short* __restrict__ wlo,
    float* __restrict__ pfS, const int* __restrict__ flagp){
  const int isbf = *flagp;
  int idx = blockIdx.x*256 + threadIdx.x;
  if (idx < 634880){
    float val = 0.f;
    if (idx < 276480){
      int l = idx / 27648; int r = idx % 27648;
      int g = r / 13824; int r2 = r % 13824;
      int kb = r2 / 4608; int r3 = r2 % 4608;
      int n144 = r3 / 32; int kk = r3 % 32;
      int sec = n144 / 48; int n = n144 % 48;
      int k = kb*32 + kk;
      if (k < 80 && n < 40){
        const void* src = (sec == 0) ? Wq : (sec == 1) ? Wk : Wv;
        val = ldf(src, (long)l*6400 + k*80 + g*40 + n, isbf);
      }
    } else if (idx < 353280){
      int r = idx - 276480;
      int l = r / 7680; int r2 = r % 7680;
      int kb = r2 / 2560; int n = (r2 % 2560) / 32; int kk = r2 % 32;
      int k = kb*32 + kk;
      if (k < 80) val = ldf(Wo, (long)l*6400 + k*80 + n, isbf);
    } else if (idx < 506880){
      int r = idx - 353280;
      int l = r / 15360; int r2 = r % 15360;
      int kb = r2 / 5120; int n = (r2 % 5120) / 32; int kk = r2 % 32;
      int k = kb*32 + kk;
      if (k < 80) val = ldf(W1, (long)l*12800 + k*160 + n, isbf);
    } else {
      int r = idx - 506880;
      int l = r / 12800; int r2 = r % 12800;
      int kb = r2 / 2560; int n = (r2 % 2560) / 32; int kk = r2 % 32;
      int k = kb*32 + kk;   // < 160 always
      val = ldf(W2, (long)l*12800 + k*80 + n, isbf);
    }
    union{float f; unsigned u;} t; t.f = val;
    unsigned hu = t.u & 0xffff0000u;
    whi[idx] = (short)(hu >> 16);
    union{unsigned u; float f;} hf; hf.u = hu;
    union{float f; unsigned u;} t2; t2.f = val - hf.f;
    wlo[idx] = (short)(t2.u >> 16);
    return;
  }
  int p = idx - 634880;
  if (p < 8144){
    float v;
    if      (p < 800)  v = ldf(bo,  p,        isbf);
    else if (p < 2400) v = ldf(b1,  p-800,    isbf);
    else if (p < 3200) v = ldf(b2,  p-2400,   isbf);
    else if (p < 3920) v = ldf(We,  p-3200,   isbf);
    else if (p < 4000) v = ldf(be,  p-3920,   isbf);
    else if (p < 7200) v = ldf(Wr0, p-4000,   isbf);
    else if (p < 7240) v = ldf(br0, p-7200,   isbf);
    else if (p < 8040) v = ldf(Wr1, p-7240,   isbf);
    else if (p < 8060) v = ldf(br1, p-8040,   isbf);
    else if (p < 8140) v = ldf(Wr2, p-8060,   isbf);
    else               v = ldf(br2, p-8140,   isbf);
    pfS[p] = v;
  }
}

// ---------------- embedding ----------------
__global__ __launch_bounds__(256) void k_embed(const void* __restrict__ x,
    const float* __restrict__ WeF, const float* __restrict__ beF,
    float* __restrict__ h, const int* __restrict__ flagp){
  __shared__ float Wl[720];
  __shared__ float bl[80];
  const int isbf = *flagp;
  int tid = threadIdx.x;
  for (int i = tid; i < 720; i += 256) Wl[i] = WeF[i];
  if (tid < 80) bl[tid] = beF[tid];
  __syncthreads();
  long idx = (long)blockIdx.x*256 + tid;
  int n = (int)(idx / 80); int c = (int)(idx - (long)n*80);
  float s = bl[c];
  #pragma unroll
  for (int k = 0; k < 9; k++) s = fmaf(ldf(x, (long)n*9 + k, isbf), Wl[k*80 + c], s);
  h[idx] = s;
}

// ---------------- split-bf16 MFMA GEMM (no LDS, no barriers) ----------------
// Each wave: 16 rows x NT 16-col tiles. A fp32 (split in-reg), W pre-split/swizzled.
// QKV=1: NT=9 => 3 sections of 48 (40 real), out + sec*slotArg, row stride 40.
// QKV=0: contiguous Nout=NT*16, ldc=slotArg; optional bias/relu/resid.
template<int NKB, int NT, int QKV>
__global__ __launch_bounds__(256) void k_mfma(
    const float* __restrict__ A, const float* __restrict__ A2, int ksplit, int lda, int Kreal,
    const short* __restrict__ Whi, const short* __restrict__ Wlo,
    const float* __restrict__ bias, const float* __restrict__ resid, int relu,
    float* __restrict__ out, long slotArg){
  const int tid  = threadIdx.x;
  const int w    = tid >> 6;
  const int lane = tid & 63;
  const int m16  = lane & 15;
  const int q    = lane >> 4;
  int rowA = blockIdx.x*64 + w*16 + m16;
  int rowAc = rowA < N_NODES ? rowA : N_NODES-1;

  f32x4 acc[NT];
  #pragma unroll
  for (int t = 0; t < NT; t++) acc[t] = (f32x4){0.f,0.f,0.f,0.f};

  #pragma unroll
  for (int kb = 0; kb < NKB; kb++){
    int k0 = kb*32 + q*8;
    short8 ahi = (short8)0, alo = (short8)0;
    if (k0 < Kreal){
      const float* p = (k0 < ksplit) ? (A  + (long)rowAc*lda + k0)
                                     : (A2 + (long)rowAc*lda + (k0 - ksplit));
      split8(p, ahi, alo);
    }
    #pragma unroll
    for (int t = 0; t < NT; t++){
      long wi = ((long)(kb*(NT*16) + t*16 + m16))*32 + q*8;
      short8 bhi = *(const short8*)(Whi + wi);
      short8 blo = *(const short8*)(Wlo + wi);
      acc[t] = __builtin_amdgcn_mfma_f32_16x16x32_bf16(alo, bhi, acc[t], 0, 0, 0);
      acc[t] = __builtin_amdgcn_mfma_f32_16x16x32_bf16(ahi, blo, acc[t], 0, 0, 0);
      acc[t] = __builtin_amdgcn_mfma_f32_16x16x32_bf16(ahi, bhi, acc[t], 0, 0, 0);
    }
  }

  int rowO = blockIdx.x*64 + w*16 + q*4;
  #pragma unroll
  for (int t = 0; t < NT; t++){
    if (QKV){
      int sec = t/3; int c = (t%3)*16 + m16;
      if (c < 40){
        float* ob = out + (long)sec*slotArg;
        #pragma unroll
        for (int rg = 0; rg < 4; rg++){
          int r = rowO + rg;
          if (r < N_NODES) ob[(long)r*40 + c] = acc[t][rg];
        }
      }
    } else {
      int col = t*16 + m16;
      float b = bias ? bias[col] : 0.f;
      #pragma unroll
      for (int rg = 0; rg < 4; rg++){
        int r = rowO + rg;
        if (r < N_NODES){
          float val = acc[t][rg] + b;
          if (relu) val = fmaxf(val, 0.f);
          long o = (long)r*slotArg + col;
          if (resid) val += resid[o];
          out[o] = val;
        }
      }
    }
  }
}

// ---------------- edge-softmax attention, fp32, half-head pass (4 heads) -----------
__global__ __launch_bounds__(256) void k_attn(
    float* __restrict__ Qg, const float* __restrict__ Kg, const float* __restrict__ Vg,
    const int* __restrict__ rowptr, const unsigned short* __restrict__ c16,
    const unsigned char* __restrict__ c8){
  int id = blockIdx.x*256 + threadIdx.x;
  int n = id >> 2; int hh = id & 3;
  if (n >= N_NODES) return;
  float* qp = Qg + (long)n*40 + hh*10;
  float qv[10];
  #pragma unroll
  for (int i = 0; i < 5; i++){ float2 t = *(const float2*)(qp + 2*i); qv[2*i]=t.x; qv[2*i+1]=t.y; }
  float acc[10];
  #pragma unroll
  for (int i = 0; i < 10; i++) acc[i] = 0.f;
  float z = 0.f;
  int e0 = rowptr[n], e1 = rowptr[n+1];
  for (int j = e0; j < e1; j++){
    int src = (int)c16[j] | ((int)c8[j] << 16);
    const float* kp = Kg + (long)src*40 + hh*10;
    const float* vp = Vg + (long)src*40 + hh*10;
    float dot = 0.f;
    #pragma unroll
    for (int i = 0; i < 5; i++){
      float2 kv = *(const float2*)(kp + 2*i);
      dot = fmaf(kv.x, qv[2*i], dot);
      dot = fmaf(kv.y, qv[2*i+1], dot);
    }
    float sc = fminf(fmaxf(dot * 0.31622776601683794f, -5.f), 5.f);
    float s = __expf(sc);
    z += s;
    #pragma unroll
    for (int i = 0; i < 5; i++){
      float2 vv = *(const float2*)(vp + 2*i);
      acc[2*i]   = fmaf(s, vv.x, acc[2*i]);
      acc[2*i+1] = fmaf(s, vv.y, acc[2*i+1]);
    }
  }
  float inv = 1.f / (z + 1e-6f);
  #pragma unroll
  for (int i = 0; i < 5; i++){
    float2 o; o.x = acc[2*i]*inv; o.y = acc[2*i+1]*inv;
    *(float2*)(qp + 2*i) = o;
  }
}

// ---------------- MLP readout 80->40->20->4, fp32 output ----------------
__global__ __launch_bounds__(256) void k_readout(const float* __restrict__ h,
    const float* __restrict__ roF,
    float* __restrict__ out){
  __shared__ float w0[3200], w1[800], w2[80], bb0[40], bb1[20], bb2[4];
  int tid = threadIdx.x;
  for (int i = tid; i < 3200; i += 256) w0[i] = roF[i];
  for (int i = tid; i < 800;  i += 256) w1[i] = roF[3240 + i];
  if (tid < 80) w2[tid]  = roF[4060 + tid];
  if (tid < 40) bb0[tid] = roF[3200 + tid];
  if (tid < 20) bb1[tid] = roF[4040 + tid];
  if (tid < 4)  bb2[tid] = roF[4140 + tid];
  __syncthreads();
  int n = blockIdx.x*256 + tid;
  if (n >= N_NODES) return;
  float t0[40];
  #pragma unroll
  for (int c = 0; c < 40; c++) t0[c] = bb0[c];
  for (int k4 = 0; k4 < 20; k4++){
    float4 hv = *(const float4*)(h + (size_t)n*80 + k4*4);
    float hx[4] = {hv.x, hv.y, hv.z, hv.w};
    #pragma unroll
    for (int j = 0; j < 4; j++){
      int k = k4*4 + j;
      #pragma unroll
      for (int c = 0; c < 40; c++) t0[c] = fmaf(hx[j], w0[k*40 + c], t0[c]);
    }
  }
  float t1[20];
  #pragma unroll
  for (int c = 0; c < 20; c++) t1[c] = bb1[c];
  for (int k = 0; k < 40; k++){
    float a = fmaxf(t0[k], 0.f);
    #pragma unroll
    for (int c = 0; c < 20; c++) t1[c] = fmaf(a, w1[k*20 + c], t1[c]);
  }
  float o[4];
  #pragma unroll
  for (int c = 0; c < 4; c++) o[c] = bb2[c];
  for (int k = 0; k < 20; k++){
    float a = fmaxf(t1[k], 0.f);
    #pragma unroll
    for (int c = 0; c < 4; c++) o[c] = fmaf(a, w2[k*4 + c], o[c]);
  }
  #pragma unroll
  for (int c = 0; c < 4; c++) out[n*4 + c] = o[c];
}

// ---------------- launch ----------------
extern "C" void kernel_launch(void* const* d_in, const int* in_sizes, int n_in,
                              void* d_out, int out_size, void* d_ws, size_t ws_size,
                              hipStream_t stream){
  const void* x   = d_in[0];
  const int*  ei  = (const int*)d_in[1];
  const void* We  = d_in[2];
  const void* be  = d_in[3];
  const void* Wq  = d_in[4];
  const void* Wk  = d_in[5];
  const void* Wv  = d_in[6];
  const void* Wo  = d_in[7];
  const void* bo  = d_in[8];
  const void* W1  = d_in[9];
  const void* b1  = d_in[10];
  const void* W2  = d_in[11];
  const void* b2  = d_in[12];
  const void* Wr0 = d_in[13];
  const void* br0 = d_in[14];
  const void* Wr1 = d_in[15];
  const void* br1 = d_in[16];
  const void* Wr2 = d_in[17];
  const void* br2 = d_in[18];

  char* ws = (char*)d_ws;
  int*   flag   = (int*)(ws + 0);
  int*   eflag  = (int*)(ws + 4);
  int*   bsum   = (int*)(ws + 64);                 // 98 ints
  float* h      = (float*)(ws + 1024);             // 32,000,000
  float* B      = (float*)(ws + 32001024);         // 64,000,000 (4 slots x 4e6 floats)
  short* Whi    = (short*)(ws + 96001024);         // 634880*2 = 1,269,760
  short* Wlo    = (short*)(ws + 97270784);         // 1,269,760
  float* pfS    = (float*)(ws + 98540544);         // 32,576
  int*   rowptr = (int*)(ws + 98573120);           // 400,004
  unsigned short* c16 = (unsigned short*)(ws + 98973124);  // 2,000,000
  unsigned char*  c8  = (unsigned char*)(ws + 100973124);  // 1,000,000 -> end 101,973,124
  int*   cursor = (int*)B;                         // aliases B (dead before layers)
  float* out    = (float*)d_out;

  const long SLOT = 4000000;
  const float* boF = pfS + 0;
  const float* b1F = pfS + 800;
  const float* b2F = pfS + 2400;
  const float* WeF = pfS + 3200;
  const float* beF = pfS + 3920;
  const float* roF = pfS + 4000;

  k_detect<<<1, 256, 0, stream>>>((const unsigned*)x, ei, flag, eflag);
  hipMemsetAsync(cursor, 0, N_NODES*sizeof(int), stream);
  k_count<<<(N_EDGES+255)/256, 256, 0, stream>>>(ei, cursor, eflag);
  k_scan1<<<98, 1024, 0, stream>>>(cursor, rowptr, bsum);
  k_scan2<<<1, 128, 0, stream>>>(bsum, rowptr);
  k_scan3<<<98, 1024, 0, stream>>>(rowptr, cursor, bsum);
  k_fill<<<(N_EDGES+255)/256, 256, 0, stream>>>(ei, cursor, c16, c8, eflag);
  k_prep<<<2512, 256, 0, stream>>>(Wq, Wk, Wv, Wo, W1, W2, bo, b1, b2, We, be,
                                   Wr0, br0, Wr1, br1, Wr2, br2, Whi, Wlo, pfS, flag);
  k_embed<<<(N_NODES*80)/256, 256, 0, stream>>>(x, WeF, beF, h, flag);

  const int gblk = (N_NODES + 63) / 64;     // 1563
  const int ablk = (N_NODES*4 + 255) / 256; // 1563
  for (int l = 0; l < NLAYERS; l++){
    for (int g = 0; g < 2; g++){
      // QKV heads g*4..g*4+3 -> slots g, g+1, g+2 ([N,40] each)
      k_mfma<3,9,1><<<gblk, 256, 0, stream>>>(
          h, h, 80, 80, 80,
          Whi + (l*2+g)*13824, Wlo + (l*2+g)*13824,
          nullptr, nullptr, 0,
          B + g*SLOT, SLOT);
      k_attn<<<ablk, 256, 0, stream>>>(
          B + g*SLOT, B + (g+1)*SLOT, B + (g+2)*SLOT, rowptr, c16, c8);
    }
    // O-proj + residual: h += [attn0|attn1] @ Wo + bo
    k_mfma<3,5,0><<<gblk, 256, 0, stream>>>(
        B, B + SLOT, 40, 40, 80,
        Whi + 276480 + l*7680, Wlo + 276480 + l*7680,
        boF + l*80, h, 0,
        h, 80);
    // FFN1: B = relu(h @ W1 + b1)  [N,160]
    k_mfma<3,10,0><<<gblk, 256, 0, stream>>>(
        h, h, 80, 80, 80,
        Whi + 353280 + l*15360, Wlo + 353280 + l*15360,
        b1F + l*160, nullptr, 1,
        B, 160);
    // FFN2 + residual: h += B @ W2 + b2
    k_mfma<5,5,0><<<gblk, 256, 0, stream>>>(
        B, B, 160, 160, 160,
        Whi + 506880 + l*12800, Wlo + 506880 + l*12800,
        b2F + l*80, h, 0,
        h, 80);
  }
  k_readout<<<(N_NODES+255)/256, 256, 0, stream>>>(h, roF, out);
}

// Round 8
// 3591.034 us; speedup vs baseline: 1.9994x; 1.0830x over previous
//
#include <hip/hip_runtime.h>
#include <hip/hip_bf16.h>

#define N_NODES 100000
#define N_EDGES 1000000
#define NLAYERS 10

typedef __hip_bfloat16 bf16;
typedef __attribute__((ext_vector_type(8))) short short8;
typedef __attribute__((ext_vector_type(4))) float f32x4;

// flag-aware float load: isbf=1 -> treat p as bf16 array, else fp32
__device__ __forceinline__ float ldf(const void* p, long i, int isbf){
  if (isbf){
    unsigned short u = ((const unsigned short*)p)[i];
    union{unsigned u; float f;} c; c.u = ((unsigned)u) << 16; return c.f;
  }
  return ((const float*)p)[i];
}

__device__ __forceinline__ int esrc(const int* ei, int e, int i64){
  return i64 ? ei[2*e] : ei[e];
}
__device__ __forceinline__ int edst(const int* ei, int e, int i64){
  return i64 ? ei[2*N_EDGES + 2*e] : ei[N_EDGES + e];
}

// split fp32 -> bf16 hi (truncate) + bf16 lo (residual)
__device__ __forceinline__ void split8(const float* p, short8& hi, short8& lo){
  float4 a = *(const float4*)p; float4 b = *(const float4*)(p+4);
  float v[8] = {a.x,a.y,a.z,a.w,b.x,b.y,b.z,b.w};
  #pragma unroll
  for (int i = 0; i < 8; i++){
    union{float f; unsigned u;} t; t.f = v[i];
    unsigned hu = t.u & 0xffff0000u;
    hi[i] = (short)(hu >> 16);
    union{unsigned u; float f;} hf; hf.u = hu;
    union{float f; unsigned u;} t2; t2.f = v[i] - hf.f;
    lo[i] = (short)(t2.u >> 16);
  }
}

// ---------------- dtype detection (parallel) ----------------
__global__ __launch_bounds__(256) void k_detect(const unsigned* __restrict__ xw,
                                                const int* __restrict__ ei,
                                                int* __restrict__ flag,
                                                int* __restrict__ eflag){
  __shared__ int s[256];
  __shared__ int t[256];
  int tid = threadIdx.x;
  int cnt = 0;
  #pragma unroll
  for (int i = 0; i < 16; i++){
    unsigned u = xw[tid*16 + i];
    unsigned lo = u & 0xffffu;
    unsigned e = (lo >> 7) & 0xff;
    if ((e >= 96 && e <= 150) || lo == 0) cnt++;
  }
  int nz = 0;
  #pragma unroll
  for (int i = 0; i < 8; i++) nz |= ei[2*(tid*8 + i) + 1];  // high words if int64
  s[tid] = cnt; t[tid] = nz; __syncthreads();
  for (int o = 128; o > 0; o >>= 1){
    if (tid < o){ s[tid] += s[tid+o]; t[tid] |= t[tid+o]; }
    __syncthreads();
  }
  if (tid == 0){
    *flag = (s[0] >= 3000) ? 1 : 0;   // bf16 ~4096 hits, f32 ~880
    *eflag = (t[0] == 0) ? 1 : 0;
  }
}

// ---------------- CSR build ----------------
__global__ __launch_bounds__(256) void k_count(const int* __restrict__ ei,
    int* __restrict__ cnt, const int* __restrict__ eflag){
  int i64 = *eflag;
  int e = blockIdx.x*256 + threadIdx.x;
  if (e < N_EDGES) atomicAdd(&cnt[edst(ei, e, i64)], 1);
}

__global__ __launch_bounds__(1024) void k_scan1(const int* __restrict__ cnt,
    int* __restrict__ rowptr, int* __restrict__ bsum){
  __shared__ int lds[1024];
  int tid = threadIdx.x;
  int i = blockIdx.x*1024 + tid;
  int v = (i < N_NODES) ? cnt[i] : 0;
  lds[tid] = v; __syncthreads();
  for (int off = 1; off < 1024; off <<= 1){
    int t = (tid >= off) ? lds[tid - off] : 0;
    __syncthreads();
    lds[tid] += t;
    __syncthreads();
  }
  if (i < N_NODES) rowptr[i] = lds[tid] - v;
  if (tid == 1023) bsum[blockIdx.x] = lds[1023];
}

__global__ __launch_bounds__(128) void k_scan2(int* __restrict__ bsum, int* __restrict__ rowptr){
  __shared__ int lds[128];
  int tid = threadIdx.x;
  int v = (tid < 98) ? bsum[tid] : 0;
  lds[tid] = v; __syncthreads();
  for (int off = 1; off < 128; off <<= 1){
    int t = (tid >= off) ? lds[tid - off] : 0;
    __syncthreads();
    lds[tid] += t;
    __syncthreads();
  }
  if (tid < 98) bsum[tid] = lds[tid] - v;
  if (tid == 127) rowptr[N_NODES] = lds[127];
}

__global__ __launch_bounds__(1024) void k_scan3(int* __restrict__ rowptr,
    int* __restrict__ cursor, const int* __restrict__ bsum){
  int i = blockIdx.x*1024 + threadIdx.x;
  if (i < N_NODES){
    int r = rowptr[i] + bsum[blockIdx.x];
    rowptr[i] = r;
    cursor[i] = r;
  }
}

__global__ __launch_bounds__(256) void k_fill(const int* __restrict__ ei,
    int* __restrict__ cursor, unsigned short* __restrict__ c16,
    unsigned char* __restrict__ c8, const int* __restrict__ eflag){
  int i64 = *eflag;
  int e = blockIdx.x*256 + threadIdx.x;
  if (e < N_EDGES){
    int d = edst(ei, e, i64);
    int p = atomicAdd(&cursor[d], 1);
    int s = esrc(ei, e, i64);
    c16[p] = (unsigned short)(s & 0xffff);
    c8[p]  = (unsigned char)(s >> 16);
  }
}

// ---------------- param prep: split+swizzle weights, small params fp32 ----------------
__global__ __launch_bounds__(256) void k_prep(
    const void* Wq, const void* Wk, const void* Wv, const void* Wo,
    const void* W1, const void* W2, const void* bo, const void* b1,
    const void* b2, const void* We, const void* be,
    const void* Wr0, const void* br0, const void* Wr1, const void* br1,
    const void* Wr2, const void* br2,
    short* __restrict__ whi, short* __restrict__ wlo,
    float* __restrict__ pfS, const int* __restrict__ flagp){
  const int isbf = *flagp;
  int idx = blockIdx.x*256 + threadIdx.x;
  if (idx < 634880){
    float val = 0.f;
    if (idx < 276480){
      int l = idx / 27648; int r = idx % 27648;
      int g = r / 13824; int r2 = r % 13824;
      int kb = r2 / 4608; int r3 = r2 % 4608;
      int n144 = r3 / 32; int kk = r3 % 32;
      int sec = n144 / 48; int n = n144 % 48;
      int k = kb*32 + kk;
      if (k < 80 && n < 40){
        const void* src = (sec == 0) ? Wq : (sec == 1) ? Wk : Wv;
        val = ldf(src, (long)l*6400 + k*80 + g*40 + n, isbf);
      }
    } else if (idx < 353280){
      int r = idx - 276480;
      int l = r / 7680; int r2 = r % 7680;
      int kb = r2 / 2560; int n = (r2 % 2560) / 32; int kk = r2 % 32;
      int k = kb*32 + kk;
      if (k < 80) val = ldf(Wo, (long)l*6400 + k*80 + n, isbf);
    } else if (idx < 506880){
      int r = idx - 353280;
      int l = r / 15360; int r2 = r % 15360;
      int kb = r2 / 5120; int n = (r2 % 5120) / 32; int kk = r2 % 32;
      int k = kb*32 + kk;
      if (k < 80) val = ldf(W1, (long)l*12800 + k*160 + n, isbf);
    } else {
      int r = idx - 506880;
      int l = r / 12800; int r2 = r % 12800;
      int kb = r2 / 2560; int n = (r2 % 2560) / 32; int kk = r2 % 32;
      int k = kb*32 + kk;
      val = ldf(W2, (long)l*12800 + k*80 + n, isbf);
    }
    union{float f; unsigned u;} t; t.f = val;
    unsigned hu = t.u & 0xffff0000u;
    whi[idx] = (short)(hu >> 16);
    union{unsigned u; float f;} hf; hf.u = hu;
    union{float f; unsigned u;} t2; t2.f = val - hf.f;
    wlo[idx] = (short)(t2.u >> 16);
    return;
  }
  int p = idx - 634880;
  if (p < 8144){
    float v;
    if      (p < 800)  v = ldf(bo,  p,        isbf);
    else if (p < 2400) v = ldf(b1,  p-800,    isbf);
    else if (p < 3200) v = ldf(b2,  p-2400,   isbf);
    else if (p < 3920) v = ldf(We,  p-3200,   isbf);
    else if (p < 4000) v = ldf(be,  p-3920,   isbf);
    else if (p < 7200) v = ldf(Wr0, p-4000,   isbf);
    else if (p < 7240) v = ldf(br0, p-7200,   isbf);
    else if (p < 8040) v = ldf(Wr1, p-7240,   isbf);
    else if (p < 8060) v = ldf(br1, p-8040,   isbf);
    else if (p < 8140) v = ldf(Wr2, p-8060,   isbf);
    else               v = ldf(br2, p-8140,   isbf);
    pfS[p] = v;
  }
}

// ---------------- embedding ----------------
__global__ __launch_bounds__(256) void k_embed(const void* __restrict__ x,
    const float* __restrict__ WeF, const float* __restrict__ beF,
    float* __restrict__ h, const int* __restrict__ flagp){
  __shared__ float Wl[720];
  __shared__ float bl[80];
  const int isbf = *flagp;
  int tid = threadIdx.x;
  for (int i = tid; i < 720; i += 256) Wl[i] = WeF[i];
  if (tid < 80) bl[tid] = beF[tid];
  __syncthreads();
  long idx = (long)blockIdx.x*256 + tid;
  int n = (int)(idx / 80); int c = (int)(idx - (long)n*80);
  float s = bl[c];
  #pragma unroll
  for (int k = 0; k < 9; k++) s = fmaf(ldf(x, (long)n*9 + k, isbf), Wl[k*80 + c], s);
  h[idx] = s;
}

// ---------------- split-bf16 MFMA GEMM (no LDS, no barriers) ----------------
template<int NKB, int NT, int QKV>
__global__ __launch_bounds__(256) void k_mfma(
    const float* __restrict__ A, const float* __restrict__ A2, int ksplit, int lda, int Kreal,
    const short* __restrict__ Whi, const short* __restrict__ Wlo,
    const float* __restrict__ bias, const float* __restrict__ resid, int relu,
    float* __restrict__ out, long slotArg){
  const int tid  = threadIdx.x;
  const int w    = tid >> 6;
  const int lane = tid & 63;
  const int m16  = lane & 15;
  const int q    = lane >> 4;
  int rowA = blockIdx.x*64 + w*16 + m16;
  int rowAc = rowA < N_NODES ? rowA : N_NODES-1;

  f32x4 acc[NT];
  #pragma unroll
  for (int t = 0; t < NT; t++) acc[t] = (f32x4){0.f,0.f,0.f,0.f};

  #pragma unroll
  for (int kb = 0; kb < NKB; kb++){
    int k0 = kb*32 + q*8;
    short8 ahi = (short8)0, alo = (short8)0;
    if (k0 < Kreal){
      const float* p = (k0 < ksplit) ? (A  + (long)rowAc*lda + k0)
                                     : (A2 + (long)rowAc*lda + (k0 - ksplit));
      split8(p, ahi, alo);
    }
    #pragma unroll
    for (int t = 0; t < NT; t++){
      long wi = ((long)(kb*(NT*16) + t*16 + m16))*32 + q*8;
      short8 bhi = *(const short8*)(Whi + wi);
      short8 blo = *(const short8*)(Wlo + wi);
      acc[t] = __builtin_amdgcn_mfma_f32_16x16x32_bf16(alo, bhi, acc[t], 0, 0, 0);
      acc[t] = __builtin_amdgcn_mfma_f32_16x16x32_bf16(ahi, blo, acc[t], 0, 0, 0);
      acc[t] = __builtin_amdgcn_mfma_f32_16x16x32_bf16(ahi, bhi, acc[t], 0, 0, 0);
    }
  }

  int rowO = blockIdx.x*64 + w*16 + q*4;
  #pragma unroll
  for (int t = 0; t < NT; t++){
    if (QKV){
      int sec = t/3; int c = (t%3)*16 + m16;
      if (c < 40){
        float* ob = out + (long)sec*slotArg;
        #pragma unroll
        for (int rg = 0; rg < 4; rg++){
          int r = rowO + rg;
          if (r < N_NODES) ob[(long)r*40 + c] = acc[t][rg];
        }
      }
    } else {
      int col = t*16 + m16;
      float b = bias ? bias[col] : 0.f;
      #pragma unroll
      for (int rg = 0; rg < 4; rg++){
        int r = rowO + rg;
        if (r < N_NODES){
          float val = acc[t][rg] + b;
          if (relu) val = fmaxf(val, 0.f);
          long o = (long)r*slotArg + col;
          if (resid) val += resid[o];
          out[o] = val;
        }
      }
    }
  }
}

// ---------------- edge-softmax attention: WAVE PER NODE ----------------
// 64 lanes = 16 edge-slots x 4 half-heads. Qg/Kg/Vg [N,40] fp32.
// Output overwrites Qg row n (row private to this wave).
__global__ __launch_bounds__(256) void k_attn(
    float* __restrict__ Qg, const float* __restrict__ Kg, const float* __restrict__ Vg,
    const int* __restrict__ rowptr, const unsigned short* __restrict__ c16,
    const unsigned char* __restrict__ c8){
  int n = (blockIdx.x*256 + threadIdx.x) >> 6;   // wave id = node (grid sized exactly)
  int lane = threadIdx.x & 63;
  int el = lane >> 2;        // edge slot 0..15
  int hh = lane & 3;         // half-head 0..3
  const float* qp = Qg + (long)n*40 + hh*10;
  float qv[10];
  #pragma unroll
  for (int i = 0; i < 5; i++){ float2 t = *(const float2*)(qp + 2*i); qv[2*i]=t.x; qv[2*i+1]=t.y; }
  float acc[10];
  #pragma unroll
  for (int i = 0; i < 10; i++) acc[i] = 0.f;
  float z = 0.f;
  int e0 = rowptr[n], e1 = rowptr[n+1];
  for (int j0 = e0; j0 < e1; j0 += 16){
    int j = j0 + el;
    bool valid = (j < e1);
    int jj = valid ? j : e0;
    int src = (int)c16[jj] | ((int)c8[jj] << 16);
    const float* kp = Kg + (long)src*40 + hh*10;
    const float* vp = Vg + (long)src*40 + hh*10;
    float dot = 0.f;
    #pragma unroll
    for (int i = 0; i < 5; i++){
      float2 kv = *(const float2*)(kp + 2*i);
      dot = fmaf(kv.x, qv[2*i], dot);
      dot = fmaf(kv.y, qv[2*i+1], dot);
    }
    float sc = fminf(fmaxf(dot * 0.31622776601683794f, -5.f), 5.f);
    float s = valid ? __expf(sc) : 0.f;
    z += s;
    #pragma unroll
    for (int i = 0; i < 5; i++){
      float2 vv = *(const float2*)(vp + 2*i);
      acc[2*i]   = fmaf(s, vv.x, acc[2*i]);
      acc[2*i+1] = fmaf(s, vv.y, acc[2*i+1]);
    }
  }
  // butterfly reduce across edge-slots (lane bits 2..5)
  #pragma unroll
  for (int m = 4; m <= 32; m <<= 1){
    z += __shfl_xor(z, m, 64);
    #pragma unroll
    for (int i = 0; i < 10; i++) acc[i] += __shfl_xor(acc[i], m, 64);
  }
  if (el == 0){
    float inv = 1.f / (z + 1e-6f);
    float* op = Qg + (long)n*40 + hh*10;
    #pragma unroll
    for (int i = 0; i < 5; i++){
      float2 o; o.x = acc[2*i]*inv; o.y = acc[2*i+1]*inv;
      *(float2*)(op + 2*i) = o;
    }
  }
}

// ---------------- MLP readout 80->40->20->4, fp32 output ----------------
__global__ __launch_bounds__(256) void k_readout(const float* __restrict__ h,
    const float* __restrict__ roF,
    float* __restrict__ out){
  __shared__ float w0[3200], w1[800], w2[80], bb0[40], bb1[20], bb2[4];
  int tid = threadIdx.x;
  for (int i = tid; i < 3200; i += 256) w0[i] = roF[i];
  for (int i = tid; i < 800;  i += 256) w1[i] = roF[3240 + i];
  if (tid < 80) w2[tid]  = roF[4060 + tid];
  if (tid < 40) bb0[tid] = roF[3200 + tid];
  if (tid < 20) bb1[tid] = roF[4040 + tid];
  if (tid < 4)  bb2[tid] = roF[4140 + tid];
  __syncthreads();
  int n = blockIdx.x*256 + tid;
  if (n >= N_NODES) return;
  float t0[40];
  #pragma unroll
  for (int c = 0; c < 40; c++) t0[c] = bb0[c];
  for (int k4 = 0; k4 < 20; k4++){
    float4 hv = *(const float4*)(h + (size_t)n*80 + k4*4);
    float hx[4] = {hv.x, hv.y, hv.z, hv.w};
    #pragma unroll
    for (int j = 0; j < 4; j++){
      int k = k4*4 + j;
      #pragma unroll
      for (int c = 0; c < 40; c++) t0[c] = fmaf(hx[j], w0[k*40 + c], t0[c]);
    }
  }
  float t1[20];
  #pragma unroll
  for (int c = 0; c < 20; c++) t1[c] = bb1[c];
  for (int k = 0; k < 40; k++){
    float a = fmaxf(t0[k], 0.f);
    #pragma unroll
    for (int c = 0; c < 20; c++) t1[c] = fmaf(a, w1[k*20 + c], t1[c]);
  }
  float o[4];
  #pragma unroll
  for (int c = 0; c < 4; c++) o[c] = bb2[c];
  for (int k = 0; k < 20; k++){
    float a = fmaxf(t1[k], 0.f);
    #pragma unroll
    for (int c = 0; c < 4; c++) o[c] = fmaf(a, w2[k*4 + c], o[c]);
  }
  #pragma unroll
  for (int c = 0; c < 4; c++) out[n*4 + c] = o[c];
}

// ---------------- launch ----------------
extern "C" void kernel_launch(void* const* d_in, const int* in_sizes, int n_in,
                              void* d_out, int out_size, void* d_ws, size_t ws_size,
                              hipStream_t stream){
  const void* x   = d_in[0];
  const int*  ei  = (const int*)d_in[1];
  const void* We  = d_in[2];
  const void* be  = d_in[3];
  const void* Wq  = d_in[4];
  const void* Wk  = d_in[5];
  const void* Wv  = d_in[6];
  const void* Wo  = d_in[7];
  const void* bo  = d_in[8];
  const void* W1  = d_in[9];
  const void* b1  = d_in[10];
  const void* W2  = d_in[11];
  const void* b2  = d_in[12];
  const void* Wr0 = d_in[13];
  const void* br0 = d_in[14];
  const void* Wr1 = d_in[15];
  const void* br1 = d_in[16];
  const void* Wr2 = d_in[17];
  const void* br2 = d_in[18];

  char* ws = (char*)d_ws;
  int*   flag   = (int*)(ws + 0);
  int*   eflag  = (int*)(ws + 4);
  int*   bsum   = (int*)(ws + 64);                 // 98 ints
  float* h      = (float*)(ws + 1024);             // 32,000,000
  float* B      = (float*)(ws + 32001024);         // 64,000,000 (4 slots x 4e6 floats)
  short* Whi    = (short*)(ws + 96001024);         // 1,269,760
  short* Wlo    = (short*)(ws + 97270784);         // 1,269,760
  float* pfS    = (float*)(ws + 98540544);         // 32,576
  int*   rowptr = (int*)(ws + 98573120);           // 400,004
  unsigned short* c16 = (unsigned short*)(ws + 98973124);  // 2,000,000
  unsigned char*  c8  = (unsigned char*)(ws + 100973124);  // 1,000,000 -> end 101,973,124
  int*   cursor = (int*)B;                         // aliases B (dead before layers)
  float* out    = (float*)d_out;

  const long SLOT = 4000000;
  const float* boF = pfS + 0;
  const float* b1F = pfS + 800;
  const float* b2F = pfS + 2400;
  const float* WeF = pfS + 3200;
  const float* beF = pfS + 3920;
  const float* roF = pfS + 4000;

  k_detect<<<1, 256, 0, stream>>>((const unsigned*)x, ei, flag, eflag);
  hipMemsetAsync(cursor, 0, N_NODES*sizeof(int), stream);
  k_count<<<(N_EDGES+255)/256, 256, 0, stream>>>(ei, cursor, eflag);
  k_scan1<<<98, 1024, 0, stream>>>(cursor, rowptr, bsum);
  k_scan2<<<1, 128, 0, stream>>>(bsum, rowptr);
  k_scan3<<<98, 1024, 0, stream>>>(rowptr, cursor, bsum);
  k_fill<<<(N_EDGES+255)/256, 256, 0, stream>>>(ei, cursor, c16, c8, eflag);
  k_prep<<<2512, 256, 0, stream>>>(Wq, Wk, Wv, Wo, W1, W2, bo, b1, b2, We, be,
                                   Wr0, br0, Wr1, br1, Wr2, br2, Whi, Wlo, pfS, flag);
  k_embed<<<(N_NODES*80)/256, 256, 0, stream>>>(x, WeF, beF, h, flag);

  const int gblk = (N_NODES + 63) / 64;   // 1563
  const int ablk = N_NODES / 4;           // 25000 blocks: 4 waves/block, wave/node
  for (int l = 0; l < NLAYERS; l++){
    for (int g = 0; g < 2; g++){
      k_mfma<3,9,1><<<gblk, 256, 0, stream>>>(
          h, h, 80, 80, 80,
          Whi + (l*2+g)*13824, Wlo + (l*2+g)*13824,
          nullptr, nullptr, 0,
          B + g*SLOT, SLOT);
      k_attn<<<ablk, 256, 0, stream>>>(
          B + g*SLOT, B + (g+1)*SLOT, B + (g+2)*SLOT, rowptr, c16, c8);
    }
    k_mfma<3,5,0><<<gblk, 256, 0, stream>>>(
        B, B + SLOT, 40, 40, 80,
        Whi + 276480 + l*7680, Wlo + 276480 + l*7680,
        boF + l*80, h, 0,
        h, 80);
    k_mfma<3,10,0><<<gblk, 256, 0, stream>>>(
        h, h, 80, 80, 80,
        Whi + 353280 + l*15360, Wlo + 353280 + l*15360,
        b1F + l*160, nullptr, 1,
        B, 160);
    k_mfma<5,5,0><<<gblk, 256, 0, stream>>>(
        B, B, 160, 160, 160,
        Whi + 506880 + l*12800, Wlo + 506880 + l*12800,
        b2F + l*80, h, 0,
        h, 80);
  }
  k_readout<<<(N_NODES+255)/256, 256, 0, stream>>>(h, roF, out);
}